// Round 2
// baseline (262.332 us; speedup 1.0000x reference)
//
#include <hip/hip_runtime.h>

// ---------------------------------------------------------------------------
// out[n] = x_n^T A x_n / (x_n^T x_n),  A = Re(U^H Z U), U = full circuit unitary
// Kernel 1: simulate circuit on 128 basis columns -> U (complex fp32) in ws
// Kernel 2: A_ij = sum_k z_k (Ur_ki Ur_kj + Ui_ki Ui_kj) -> bf16 A in ws
// Kernel 3: bf16 MFMA GEMM y = A x fused with dot/norm epilogue (memory-bound)
//
// R1 -> R2: A moved from 128 VGPRs of per-wave fragments (spilled under
// launch_bounds(256,2)) into 32KB LDS with XOR-swizzled 16B chunks
// (2-way bank aliasing = free per m136). No software prefetch; latency
// hidden by 4 waves/SIMD occupancy instead.
// ---------------------------------------------------------------------------

#define N_QUBITS 7
#define DIM 128
#define N_LAYERS 4
#define BATCH 262144
#define NT (BATCH / 64)   // 4096 tiles of 64 batch columns

typedef short short8 __attribute__((ext_vector_type(8)));
typedef float f32x4 __attribute__((ext_vector_type(4)));

__device__ __forceinline__ unsigned short f2bf(float f) {
  unsigned u = __builtin_bit_cast(unsigned, f);
  u += 0x7fffu + ((u >> 16) & 1u);   // round-to-nearest-even
  return (unsigned short)(u >> 16);
}

__device__ __forceinline__ short8 pack_bf16(float4 a, float4 b) {
  short8 r;
  r[0] = (short)f2bf(a.x); r[1] = (short)f2bf(a.y);
  r[2] = (short)f2bf(a.z); r[3] = (short)f2bf(a.w);
  r[4] = (short)f2bf(b.x); r[5] = (short)f2bf(b.y);
  r[6] = (short)f2bf(b.z); r[7] = (short)f2bf(b.w);
  return r;
}

// ---------------------------------------------------------------------------
// Kernel 1: one block (64 threads) per column c. State (128 complex) in LDS.
// Qubit w <-> bit (6-w) of the flattened index (axis 1 = qubit 0 = MSB).
// ---------------------------------------------------------------------------
__global__ void sim_columns(const float* __restrict__ W,
                            float* __restrict__ Ur, float* __restrict__ Ui) {
  __shared__ float sr[DIM], si[DIM];
  const int c = blockIdx.x;
  const int t = threadIdx.x;  // 0..63

  sr[t] = (t == c) ? 1.f : 0.f;        si[t] = 0.f;
  sr[t + 64] = (t + 64 == c) ? 1.f : 0.f;  si[t + 64] = 0.f;
  __syncthreads();

  for (int l = 0; l < N_LAYERS; ++l) {
    for (int w = 0; w < N_QUBITS; ++w) {
      const float phi = W[(l * 7 + w) * 3 + 0];
      const float th  = W[(l * 7 + w) * 3 + 1];
      const float om  = W[(l * 7 + w) * 3 + 2];
      const float ch = __cosf(0.5f * th), sh = __sinf(0.5f * th);
      const float ap = 0.5f * (phi + om), am = 0.5f * (phi - om);
      const float cap = __cosf(ap), sap = __sinf(ap);
      const float cam = __cosf(am), sam = __sinf(am);
      const float ar =  cap * ch, ai = -sap * ch;
      const float br = -cam * sh, bi = -sam * sh;
      const float cr =  cam * sh, ci = -sam * sh;
      const float dr =  cap * ch, di =  sap * ch;

      const int m = 1 << (6 - w);
      const int i0 = ((t & ~(m - 1)) << 1) | (t & (m - 1));
      const int i1 = i0 | m;
      const float x0r = sr[i0], x0i = si[i0];
      const float x1r = sr[i1], x1i = si[i1];
      __syncthreads();
      sr[i0] = ar * x0r - ai * x0i + br * x1r - bi * x1i;
      si[i0] = ar * x0i + ai * x0r + br * x1i + bi * x1r;
      sr[i1] = cr * x0r - ci * x0i + dr * x1r - di * x1i;
      si[i1] = cr * x0i + ci * x0r + dr * x1i + di * x1r;
      __syncthreads();
    }
    const int r = (l % (N_QUBITS - 1)) + 1;  // ranges [1,2,3,4]
    for (int w = 0; w < N_QUBITS; ++w) {
      const int ctrl = w, tgt = (w + r) % N_QUBITS;
      const int cmask = 1 << (6 - ctrl), tmask = 1 << (6 - tgt);
      const int i0 = ((t & ~(tmask - 1)) << 1) | (t & (tmask - 1));  // tgt bit = 0
      const int i1 = i0 | tmask;
      const float a0r = sr[i0], a0i = si[i0];
      const float a1r = sr[i1], a1i = si[i1];
      __syncthreads();
      if (i0 & cmask) {  // control set: swap target pair
        sr[i0] = a1r; si[i0] = a1i;
        sr[i1] = a0r; si[i1] = a0i;
      }
      __syncthreads();
    }
  }
  Ur[(size_t)t * DIM + c]        = sr[t];
  Ui[(size_t)t * DIM + c]        = si[t];
  Ur[(size_t)(t + 64) * DIM + c] = sr[t + 64];
  Ui[(size_t)(t + 64) * DIM + c] = si[t + 64];
}

// ---------------------------------------------------------------------------
// Kernel 2: A_ij = sum_k z_k (Ur[k][i]Ur[k][j] + Ui[k][i]Ui[k][j]), bf16 out.
// z_k = (-1)^(b0 xor b6), b0 = bit6 (MSB), b6 = bit0 (LSB).
// ---------------------------------------------------------------------------
__global__ void build_A(const float* __restrict__ Ur, const float* __restrict__ Ui,
                        unsigned short* __restrict__ Ab) {
  const int idx = blockIdx.x * blockDim.x + threadIdx.x;  // 0..16383
  const int i = idx >> 7, j = idx & 127;
  float s = 0.f;
#pragma unroll 4
  for (int k = 0; k < DIM; ++k) {
    const float zk = (((k >> 6) ^ k) & 1) ? -1.f : 1.f;
    s += zk * (Ur[k * DIM + i] * Ur[k * DIM + j] + Ui[k * DIM + i] * Ui[k * DIM + j]);
  }
  Ab[idx] = f2bf(s);
}

// ---------------------------------------------------------------------------
// Kernel 3: main GEMM + epilogue. Block = 4 waves; wave handles 16 batch
// columns per tile iteration. A lives in LDS (32KB), XOR-swizzled chunks.
//   A-frag: lane holds A[m = 16t + (lane&15)][k = 32kt + (lane>>4)*8 + j]
//   B-frag: lane holds x[n][k = 32kt + (lane>>4)*8 + j]  (n = lane&15 col)
//   C/D:    acc[t][r] = y[16t + (lane>>4)*4 + r][lane&15]
// LDS layout: row m = 16 chunks of 16B; chunk c stored at slot c ^ (m & 15).
// ds_read_b128 bank pattern: bank-group = ((4kt+g)^n16) % 8 -> each group hit
// by exactly 2 of 16 same-g lanes = 2-way = free (m136).
// ---------------------------------------------------------------------------
__global__ __launch_bounds__(256, 4) void vqa_main(const float* __restrict__ X,
                                                   const unsigned short* __restrict__ Ab,
                                                   float* __restrict__ out) {
  __shared__ unsigned short As[DIM * DIM];  // 32 KB

  const int tid = threadIdx.x;
  const int lane = tid & 63;
  const int wave = tid >> 6;
  const int n16 = lane & 15;
  const int g = lane >> 4;

  // ---- fill A into LDS with chunk swizzle (one-time, L2-hot source) ----
#pragma unroll
  for (int i = 0; i < 8; ++i) {
    const int q = tid + 256 * i;          // global 16B-chunk id, 0..2047
    const int m = q >> 4, c = q & 15;
    const short8 v = *reinterpret_cast<const short8*>(Ab + q * 8);
    *reinterpret_cast<short8*>(As + m * DIM + ((c ^ (m & 15)) << 3)) = v;
  }
  __syncthreads();

  // per-kt LDS base (halfword index); t adds t*2048 (immediate offsets)
  const unsigned short* abase[4];
#pragma unroll
  for (int kt = 0; kt < 4; ++kt)
    abase[kt] = As + n16 * DIM + ((((4 * kt + g) ^ n16)) << 3);

  for (int tile = blockIdx.x; tile < NT; tile += gridDim.x) {
    const int n = tile * 64 + wave * 16 + n16;

    // load this lane's 32 fp32 of x and pack to B-fragments
    const float* xp = X + (size_t)n * DIM + g * 8;
    short8 bfrag[4];
#pragma unroll
    for (int kt = 0; kt < 4; ++kt) {
      const float4 lo = *reinterpret_cast<const float4*>(xp + kt * 32);
      const float4 hi = *reinterpret_cast<const float4*>(xp + kt * 32 + 4);
      bfrag[kt] = pack_bf16(lo, hi);
    }

    f32x4 acc[8];
#pragma unroll
    for (int t = 0; t < 8; ++t) acc[t] = (f32x4){0.f, 0.f, 0.f, 0.f};

#pragma unroll
    for (int kt = 0; kt < 4; ++kt) {
#pragma unroll
      for (int t = 0; t < 8; ++t) {
        const short8 af = *reinterpret_cast<const short8*>(abase[kt] + t * 16 * DIM);
        acc[t] = __builtin_amdgcn_mfma_f32_16x16x32_bf16(af, bfrag[kt], acc[t], 0, 0, 0);
      }
    }

    // epilogue: dot = sum_m x[m][n] y[m][n]; nrm = sum_m x[m][n]^2 (L1 re-read)
    const float* xe = X + (size_t)n * DIM + g * 4;
    float dot = 0.f, nrm = 0.f;
#pragma unroll
    for (int t = 0; t < 8; ++t) {
      const float4 xr = *reinterpret_cast<const float4*>(xe + t * 16);
      dot += xr.x * acc[t][0] + xr.y * acc[t][1] + xr.z * acc[t][2] + xr.w * acc[t][3];
      nrm += xr.x * xr.x + xr.y * xr.y + xr.z * xr.z + xr.w * xr.w;
    }
    dot += __shfl_xor(dot, 16, 64);
    dot += __shfl_xor(dot, 32, 64);
    nrm += __shfl_xor(nrm, 16, 64);
    nrm += __shfl_xor(nrm, 32, 64);
    if (lane < 16) out[n] = dot / nrm;
  }
}

// ---------------------------------------------------------------------------
extern "C" void kernel_launch(void* const* d_in, const int* in_sizes, int n_in,
                              void* d_out, int out_size, void* d_ws, size_t ws_size,
                              hipStream_t stream) {
  const float* X = (const float*)d_in[0];   // (262144, 128) fp32
  const float* W = (const float*)d_in[1];   // (4, 7, 3) fp32
  float* out = (float*)d_out;               // (262144,) fp32

  // workspace: Ur (64KB) | Ui (64KB) | A bf16 (32KB)
  float* Ur = (float*)d_ws;
  float* Ui = Ur + DIM * DIM;
  unsigned short* Ab = (unsigned short*)(Ui + DIM * DIM);

  sim_columns<<<DIM, 64, 0, stream>>>(W, Ur, Ui);
  build_A<<<64, 256, 0, stream>>>(Ur, Ui, Ab);
  vqa_main<<<1024, 256, 0, stream>>>(X, Ab, out);
}

// Round 3
// 216.566 us; speedup vs baseline: 1.2113x; 1.2113x over previous
//
#include <hip/hip_runtime.h>

// ---------------------------------------------------------------------------
// out[n] = x_n^T A x_n / (x_n^T x_n),  A = Re(U^H Z U), U = full circuit unitary
// Kernel 1: simulate circuit on 128 basis columns -> U (complex fp32) in ws
// Kernel 2: A_ij = sum_k z_k (Ur_ki Ur_kj + Ui_ki Ui_kj) -> bf16 A in ws
// Kernel 3: bf16 MFMA GEMM y = A x fused with dot/norm epilogue (memory-bound)
//
// R2 -> R3: kill the scratch spill (WRITE_SIZE 66 MB -> ~1 MB): launch_bounds
// (256,2) so the compiler doesn't clamp to 64 VGPRs and spill; epilogue x
// re-read moved BEFORE the MFMA section (L1-hot, same lines as B-frag load)
// and held in registers -> no post-MFMA dependent HBM loads, no L2-miss
// re-fetch.
// ---------------------------------------------------------------------------

#define N_QUBITS 7
#define DIM 128
#define N_LAYERS 4
#define BATCH 262144
#define NT (BATCH / 64)   // 4096 tiles of 64 batch columns

typedef short short8 __attribute__((ext_vector_type(8)));
typedef float f32x4 __attribute__((ext_vector_type(4)));

__device__ __forceinline__ unsigned short f2bf(float f) {
  unsigned u = __builtin_bit_cast(unsigned, f);
  u += 0x7fffu + ((u >> 16) & 1u);   // round-to-nearest-even
  return (unsigned short)(u >> 16);
}

__device__ __forceinline__ short8 pack_bf16(float4 a, float4 b) {
  short8 r;
  r[0] = (short)f2bf(a.x); r[1] = (short)f2bf(a.y);
  r[2] = (short)f2bf(a.z); r[3] = (short)f2bf(a.w);
  r[4] = (short)f2bf(b.x); r[5] = (short)f2bf(b.y);
  r[6] = (short)f2bf(b.z); r[7] = (short)f2bf(b.w);
  return r;
}

// ---------------------------------------------------------------------------
// Kernel 1: one block (64 threads) per column c. State (128 complex) in LDS.
// Qubit w <-> bit (6-w) of the flattened index (axis 1 = qubit 0 = MSB).
// ---------------------------------------------------------------------------
__global__ void sim_columns(const float* __restrict__ W,
                            float* __restrict__ Ur, float* __restrict__ Ui) {
  __shared__ float sr[DIM], si[DIM];
  const int c = blockIdx.x;
  const int t = threadIdx.x;  // 0..63

  sr[t] = (t == c) ? 1.f : 0.f;        si[t] = 0.f;
  sr[t + 64] = (t + 64 == c) ? 1.f : 0.f;  si[t + 64] = 0.f;
  __syncthreads();

  for (int l = 0; l < N_LAYERS; ++l) {
    for (int w = 0; w < N_QUBITS; ++w) {
      const float phi = W[(l * 7 + w) * 3 + 0];
      const float th  = W[(l * 7 + w) * 3 + 1];
      const float om  = W[(l * 7 + w) * 3 + 2];
      const float ch = __cosf(0.5f * th), sh = __sinf(0.5f * th);
      const float ap = 0.5f * (phi + om), am = 0.5f * (phi - om);
      const float cap = __cosf(ap), sap = __sinf(ap);
      const float cam = __cosf(am), sam = __sinf(am);
      const float ar =  cap * ch, ai = -sap * ch;
      const float br = -cam * sh, bi = -sam * sh;
      const float cr =  cam * sh, ci = -sam * sh;
      const float dr =  cap * ch, di =  sap * ch;

      const int m = 1 << (6 - w);
      const int i0 = ((t & ~(m - 1)) << 1) | (t & (m - 1));
      const int i1 = i0 | m;
      const float x0r = sr[i0], x0i = si[i0];
      const float x1r = sr[i1], x1i = si[i1];
      __syncthreads();
      sr[i0] = ar * x0r - ai * x0i + br * x1r - bi * x1i;
      si[i0] = ar * x0i + ai * x0r + br * x1i + bi * x1r;
      sr[i1] = cr * x0r - ci * x0i + dr * x1r - di * x1i;
      si[i1] = cr * x0i + ci * x0r + dr * x1i + di * x1r;
      __syncthreads();
    }
    const int r = (l % (N_QUBITS - 1)) + 1;  // ranges [1,2,3,4]
    for (int w = 0; w < N_QUBITS; ++w) {
      const int ctrl = w, tgt = (w + r) % N_QUBITS;
      const int cmask = 1 << (6 - ctrl), tmask = 1 << (6 - tgt);
      const int i0 = ((t & ~(tmask - 1)) << 1) | (t & (tmask - 1));  // tgt bit = 0
      const int i1 = i0 | tmask;
      const float a0r = sr[i0], a0i = si[i0];
      const float a1r = sr[i1], a1i = si[i1];
      __syncthreads();
      if (i0 & cmask) {  // control set: swap target pair
        sr[i0] = a1r; si[i0] = a1i;
        sr[i1] = a0r; si[i1] = a0i;
      }
      __syncthreads();
    }
  }
  Ur[(size_t)t * DIM + c]        = sr[t];
  Ui[(size_t)t * DIM + c]        = si[t];
  Ur[(size_t)(t + 64) * DIM + c] = sr[t + 64];
  Ui[(size_t)(t + 64) * DIM + c] = si[t + 64];
}

// ---------------------------------------------------------------------------
// Kernel 2: A_ij = sum_k z_k (Ur[k][i]Ur[k][j] + Ui[k][i]Ui[k][j]), bf16 out.
// z_k = (-1)^(b0 xor b6), b0 = bit6 (MSB), b6 = bit0 (LSB).
// ---------------------------------------------------------------------------
__global__ void build_A(const float* __restrict__ Ur, const float* __restrict__ Ui,
                        unsigned short* __restrict__ Ab) {
  const int idx = blockIdx.x * blockDim.x + threadIdx.x;  // 0..16383
  const int i = idx >> 7, j = idx & 127;
  float s = 0.f;
#pragma unroll 4
  for (int k = 0; k < DIM; ++k) {
    const float zk = (((k >> 6) ^ k) & 1) ? -1.f : 1.f;
    s += zk * (Ur[k * DIM + i] * Ur[k * DIM + j] + Ui[k * DIM + i] * Ui[k * DIM + j]);
  }
  Ab[idx] = f2bf(s);
}

// ---------------------------------------------------------------------------
// Kernel 3: main GEMM + epilogue. Block = 4 waves; wave handles 16 batch
// rows per tile iteration. A lives in LDS (32KB), XOR-swizzled 16B chunks
// (0 bank conflicts measured in R2).
//   A-frag: lane holds A[m = 16t + (lane&15)][k = 32kt + (lane>>4)*8 + j]
//   B-frag: lane holds x[n][k = 32kt + (lane>>4)*8 + j]  (n row = lane&15)
//   C/D:    acc[t][r] = y[16t + (lane>>4)*4 + r][lane&15]
// Epilogue x slice (x[n][16t+4g+r]) is re-read right after the B-frag load
// of the same row (L1-hot) and held in 32 VGPRs through the MFMA section.
// launch_bounds(256,2): live set ~100 regs; (256,4) made the compiler clamp
// to 64 VGPRs and spill 4KB/wave-iter to scratch (R2: WRITE_SIZE 66 MB).
// ---------------------------------------------------------------------------
__global__ __launch_bounds__(256, 2) void vqa_main(const float* __restrict__ X,
                                                   const unsigned short* __restrict__ Ab,
                                                   float* __restrict__ out) {
  __shared__ unsigned short As[DIM * DIM];  // 32 KB

  const int tid = threadIdx.x;
  const int lane = tid & 63;
  const int wave = tid >> 6;
  const int n16 = lane & 15;
  const int g = lane >> 4;

  // ---- fill A into LDS with chunk swizzle (one-time, L2-hot source) ----
#pragma unroll
  for (int i = 0; i < 8; ++i) {
    const int q = tid + 256 * i;          // global 16B-chunk id, 0..2047
    const int m = q >> 4, c = q & 15;
    const short8 v = *reinterpret_cast<const short8*>(Ab + q * 8);
    *reinterpret_cast<short8*>(As + m * DIM + ((c ^ (m & 15)) << 3)) = v;
  }
  __syncthreads();

  const unsigned short* abase[4];
#pragma unroll
  for (int kt = 0; kt < 4; ++kt)
    abase[kt] = As + n16 * DIM + (((4 * kt + g) ^ n16) << 3);

  for (int tile = blockIdx.x; tile < NT; tile += gridDim.x) {
    const int n = tile * 64 + wave * 16 + n16;
    const float* xp = X + (size_t)n * DIM;

    // B-fragment load + bf16 pack (frees the fp32 temporaries)
    short8 bfrag[4];
#pragma unroll
    for (int kt = 0; kt < 4; ++kt) {
      const float4 lo = *reinterpret_cast<const float4*>(xp + kt * 32 + g * 8);
      const float4 hi = *reinterpret_cast<const float4*>(xp + kt * 32 + g * 8 + 4);
      bfrag[kt] = pack_bf16(lo, hi);
    }

    // epilogue x slice: re-read NOW (L1-hot, same lines), hold through MFMAs
    float4 xr[8];
    float nrm = 0.f;
#pragma unroll
    for (int t = 0; t < 8; ++t) {
      xr[t] = *reinterpret_cast<const float4*>(xp + t * 16 + g * 4);
      nrm += xr[t].x * xr[t].x + xr[t].y * xr[t].y +
             xr[t].z * xr[t].z + xr[t].w * xr[t].w;
    }

    f32x4 acc[8];
#pragma unroll
    for (int t = 0; t < 8; ++t) acc[t] = (f32x4){0.f, 0.f, 0.f, 0.f};

#pragma unroll
    for (int kt = 0; kt < 4; ++kt) {
#pragma unroll
      for (int t = 0; t < 8; ++t) {
        const short8 af = *reinterpret_cast<const short8*>(abase[kt] + t * 16 * DIM);
        acc[t] = __builtin_amdgcn_mfma_f32_16x16x32_bf16(af, bfrag[kt], acc[t], 0, 0, 0);
      }
    }

    float dot = 0.f;
#pragma unroll
    for (int t = 0; t < 8; ++t) {
      dot += xr[t].x * acc[t][0] + xr[t].y * acc[t][1] +
             xr[t].z * acc[t][2] + xr[t].w * acc[t][3];
    }
    dot += __shfl_xor(dot, 16, 64);
    dot += __shfl_xor(dot, 32, 64);
    nrm += __shfl_xor(nrm, 16, 64);
    nrm += __shfl_xor(nrm, 32, 64);
    if (lane < 16) out[n] = dot / nrm;
  }
}

// ---------------------------------------------------------------------------
extern "C" void kernel_launch(void* const* d_in, const int* in_sizes, int n_in,
                              void* d_out, int out_size, void* d_ws, size_t ws_size,
                              hipStream_t stream) {
  const float* X = (const float*)d_in[0];   // (262144, 128) fp32
  const float* W = (const float*)d_in[1];   // (4, 7, 3) fp32
  float* out = (float*)d_out;               // (262144,) fp32

  // workspace: Ur (64KB) | Ui (64KB) | A bf16 (32KB)
  float* Ur = (float*)d_ws;
  float* Ui = Ur + DIM * DIM;
  unsigned short* Ab = (unsigned short*)(Ui + DIM * DIM);

  sim_columns<<<DIM, 64, 0, stream>>>(W, Ur, Ui);
  build_A<<<64, 256, 0, stream>>>(Ur, Ui, Ab);
  vqa_main<<<1024, 256, 0, stream>>>(X, Ab, out);
}